// Round 2
// baseline (3260.794 us; speedup 1.0000x reference)
//
#include <hip/hip_runtime.h>
#include <math.h>

static constexpr int HS = 64;
static constexpr int HV = 32;
static constexpr int NB = 32;
static constexpr float CUTR = 5.0f;
static constexpr float SQRT3 = 1.7320508075688772f;
static constexpr float C2C = 2.7386127875258306f; // sqrt(7.5)

// ---------------- CSR build ----------------

__global__ void count_kernel(const int* __restrict__ ei, int* __restrict__ counts, int E) {
    int e = blockIdx.x * blockDim.x + threadIdx.x;
    if (e < E) atomicAdd(&counts[ei[E + e]], 1);
}

__global__ __launch_bounds__(1024) void scan_kernel(const int* __restrict__ counts,
                                                    int* __restrict__ row_ptr,
                                                    int* __restrict__ cursor, int N) {
    __shared__ int part[1024];
    int t = threadIdx.x;
    int chunk = (N + 1023) >> 10;
    int beg = t * chunk, end = min(beg + chunk, N);
    int s = 0;
    for (int i = beg; i < end; ++i) s += counts[i];
    part[t] = s;
    __syncthreads();
    for (int off = 1; off < 1024; off <<= 1) {
        int v = (t >= off) ? part[t - off] : 0;
        __syncthreads();
        part[t] += v;
        __syncthreads();
    }
    int base = (t == 0) ? 0 : part[t - 1];
    for (int i = beg; i < end; ++i) {
        row_ptr[i] = base;
        cursor[i] = base;
        base += counts[i];
    }
    if (t == 1023) row_ptr[N] = part[1023];
}

// Per-edge record, written in dst-sorted order: 20 dwords = 80B
// [0]=src(int) [1]=gate [2..4]=d [5..9]=w(l=0) [10..14]=w(l=1) [15..19]=w(l=2)
__global__ void build_kernel(const int* __restrict__ ei, const float* __restrict__ pos,
                             const float* __restrict__ shifts, const float* __restrict__ Wr,
                             const float* __restrict__ Wrb, int* __restrict__ cursor,
                             float* __restrict__ recs, int E) {
    int e = blockIdx.x * blockDim.x + threadIdx.x;
    if (e >= E) return;
    int src = ei[e], dst = ei[E + e];
    float ev0 = pos[dst * 3 + 0] - pos[src * 3 + 0] + shifts[e * 3 + 0];
    float ev1 = pos[dst * 3 + 1] - pos[src * 3 + 1] + shifts[e * 3 + 1];
    float ev2 = pos[dst * 3 + 2] - pos[src * 3 + 2] + shifts[e * 3 + 2];
    float r = sqrtf(ev0 * ev0 + ev1 * ev1 + ev2 * ev2);
    float rinv = 1.0f / fmaxf(r, 1e-8f);
    float d0 = ev0 * rinv, d1 = ev1 * rinv, d2 = ev2 * rinv;
    float u = r * (1.0f / CUTR);
    float gate = 0.0f;
    if (u < 1.0f) {
        float inner = 1.0f - u * u;
        gate = __expf(1.0f - 1.0f / inner);
    }
    float wacc[15];
#pragma unroll
    for (int k = 0; k < 15; ++k) wacc[k] = 0.0f;
    const float inv_w = (float)NB / CUTR; // 1/width = 6.4
    for (int b = 0; b < NB; ++b) {
        float t = (r - (float)b * (CUTR / (NB - 1))) * inv_w;
        float rb = __expf(-0.5f * t * t);
#pragma unroll
        for (int k = 0; k < 15; ++k)
            wacc[k] += rb * Wr[(k / 5) * (NB * 5) + b * 5 + (k % 5)];
    }
    float tmp[20];
    ((int*)tmp)[0] = src;
    tmp[1] = gate; tmp[2] = d0; tmp[3] = d1; tmp[4] = d2;
#pragma unroll
    for (int k = 0; k < 15; ++k) tmp[5 + k] = gate * wacc[k] + Wrb[k];
    int p = atomicAdd(&cursor[dst], 1);
    float4* o = (float4*)(recs + (size_t)p * 20);
    const float4* s4 = (const float4*)tmp;
#pragma unroll
    for (int k = 0; k < 5; ++k) o[k] = s4[k];
}

// ---------------- weight composition:  Ms12[l] = Wos[l] @ Ws[l+1],  Mv12[l] = Wov[l] @ Wv[l+1]
__global__ void compose_kernel(const float* __restrict__ Ws, const float* __restrict__ Wv,
                               const float* __restrict__ Wos, const float* __restrict__ Wov,
                               float* __restrict__ Ms12, float* __restrict__ Mv12) {
    int t = blockIdx.x * blockDim.x + threadIdx.x;
    if (t < 2 * 4096) {
        int l = t >> 12;
        int idx = t & 4095;
        int j = idx >> 6, k = idx & 63;
        const float* A = Wos + l * 4096;
        const float* B = Ws + (l + 1) * 4096;
        float acc = 0.0f;
        for (int m = 0; m < 64; ++m) acc += A[j * 64 + m] * B[m * 64 + k];
        Ms12[t] = acc;
    } else if (t < 2 * 4096 + 2 * 1024) {
        int q = t - 2 * 4096;
        int l = q >> 10;
        int idx = q & 1023;
        int j = idx >> 5, k = idx & 31;
        const float* A = Wov + l * 1024;
        const float* B = Wv + (l + 1) * 1024;
        float acc = 0.0f;
        for (int m = 0; m < 32; ++m) acc += A[j * 32 + m] * B[m * 32 + k];
        Mv12[q] = acc;
    }
}

// ---------------- node transform: sp = as @ Ms ; vpT[d] = avT[d] @ Mv ----------------
// MODE 0: inputs are raw features (s: N x 64, v: N x 32 x 3 AoS) -> sp/vpT
// MODE 1: inputs are agg buffers (as: N x 64, avT: 3 planes of N x 32) -> sp/vpT
// MODE 2: like 1 but writes interleaved final output (N x 160) to sp_out
template <int MODE>
__global__ void node_transform(const float* __restrict__ s_in, const float* __restrict__ v_in,
                               const float* __restrict__ Ms, const float* __restrict__ Mv,
                               float* __restrict__ sp_out, float* __restrict__ vpT_out, int N) {
    __shared__ float sMs[64 * 64];
    __shared__ float sMv[32 * 32];
    for (int i = threadIdx.x; i < 4096; i += blockDim.x) sMs[i] = Ms[i];
    for (int i = threadIdx.x; i < 1024; i += blockDim.x) sMv[i] = Mv[i];
    __syncthreads();
    int wid = threadIdx.x >> 6, lane = threadIdx.x & 63;
    int n = blockIdx.x * (blockDim.x >> 6) + wid;
    if (n >= N) return;
    float asv = s_in[(size_t)n * 64 + lane];
    int h = lane & 31;
    float av0, av1, av2;
    if (MODE == 0) {
        av0 = v_in[(size_t)n * 96 + h * 3 + 0];
        av1 = v_in[(size_t)n * 96 + h * 3 + 1];
        av2 = v_in[(size_t)n * 96 + h * 3 + 2];
    } else {
        av0 = v_in[(size_t)n * 32 + h];
        av1 = v_in[(size_t)N * 32 + (size_t)n * 32 + h];
        av2 = v_in[(size_t)2 * N * 32 + (size_t)n * 32 + h];
    }
    float acc = 0.0f;
    for (int i = 0; i < 64; ++i)
        acc += __shfl(asv, i) * sMs[i * 64 + lane];
    float vacc0 = 0.0f, vacc1 = 0.0f, vacc2 = 0.0f;
    for (int g = 0; g < 32; ++g) {
        float b0 = __shfl(av0, g), b1 = __shfl(av1, g), b2 = __shfl(av2, g);
        float m = sMv[g * 32 + h];
        vacc0 += b0 * m; vacc1 += b1 * m; vacc2 += b2 * m;
    }
    if (MODE == 2) {
        sp_out[(size_t)n * 160 + lane] = acc;
        if (lane < 32) {
            sp_out[(size_t)n * 160 + 64 + lane * 3 + 0] = vacc0;
            sp_out[(size_t)n * 160 + 64 + lane * 3 + 1] = vacc1;
            sp_out[(size_t)n * 160 + 64 + lane * 3 + 2] = vacc2;
        }
    } else {
        sp_out[(size_t)n * 64 + lane] = acc;
        if (lane < 32) {
            vpT_out[(size_t)n * 32 + lane] = vacc0;
            vpT_out[(size_t)N * 32 + (size_t)n * 32 + lane] = vacc1;
            vpT_out[(size_t)2 * N * 32 + (size_t)n * 32 + lane] = vacc2;
        }
    }
}

// ---------------- edge aggregation: one wave per dst node ----------------
__global__ void edge_agg(const float* __restrict__ recs, const int* __restrict__ row_ptr,
                         const float* __restrict__ sp, const float* __restrict__ vpT,
                         const float* __restrict__ Uvs_l, const float* __restrict__ Usv_l,
                         float* __restrict__ as_out, float* __restrict__ avT_out,
                         int N, int wsel) {
    __shared__ float sUvs[32 * 64];
    __shared__ float sUsv[64 * 32];
    for (int i = threadIdx.x; i < 2048; i += blockDim.x) {
        sUvs[i] = Uvs_l[i];
        sUsv[i] = Usv_l[i];
    }
    __syncthreads();
    int wid = threadIdx.x >> 6, lane = threadIdx.x & 63;
    int n = blockIdx.x * (blockDim.x >> 6) + wid;
    if (n >= N) return;
    int beg = row_ptr[n], end = row_ptr[n + 1];
    const float* vp0 = vpT;
    const float* vp1 = vpT + (size_t)N * 32;
    const float* vp2 = vpT + (size_t)2 * N * 32;
    float S0 = 0.f, T10 = 0.f, T11 = 0.f, T12 = 0.f;
    float A1 = 0.f, V0 = 0.f, V1 = 0.f, V2 = 0.f;
    for (int i = beg; i < end; ++i) {
        const float* R = recs + (size_t)i * 20;
        int src = __float_as_int(R[0]);
        float g = R[1], d0 = R[2], d1 = R[3], d2 = R[4];
        float w0 = R[wsel + 0], w1 = R[wsel + 1], w2 = R[wsel + 2],
              w3 = R[wsel + 3], w4 = R[wsel + 4];
        float a = g * w0;
        float b = g * w1 * SQRT3;
        float gw2s = g * w2 * SQRT3;
        float t0 = gw2s * d0, t1 = gw2s * d1, t2 = gw2s * d2;
        float q4 = g * w4 * C2C;
        float q3 = g * w3 - q4 * (1.0f / 3.0f);
        float spc = sp[(size_t)src * 64 + lane];
        S0 += a * spc;
        T10 += t0 * spc; T11 += t1 * spc; T12 += t2 * spc;
        if (lane < 32) {
            float v0 = vp0[(size_t)src * 32 + lane];
            float v1 = vp1[(size_t)src * 32 + lane];
            float v2 = vp2[(size_t)src * 32 + lane];
            float pdot = d0 * v0 + d1 * v1 + d2 * v2;
            A1 += b * pdot;
            V0 += q3 * v0 + q4 * d0 * pdot;
            V1 += q3 * v1 + q4 * d1 * pdot;
            V2 += q3 * v2 + q4 * d2 * pdot;
        }
    }
    // agg_s[c] = S0 + sum_h A1[h] * Uvs[h,c]
    float aggs = S0;
    for (int h2 = 0; h2 < 32; ++h2)
        aggs += __shfl(A1, h2) * sUvs[h2 * 64 + lane];
    as_out[(size_t)n * 64 + lane] = aggs;
    // agg_v[h,d] = V[h,d] + sum_c T1[c,d] * Usv[c,h]
    float av0 = V0, av1 = V1, av2 = V2;
    int h = lane & 31;
    for (int c = 0; c < 64; ++c) {
        float uu = sUsv[c * 32 + h];
        av0 += __shfl(T10, c) * uu;
        av1 += __shfl(T11, c) * uu;
        av2 += __shfl(T12, c) * uu;
    }
    if (lane < 32) {
        avT_out[(size_t)n * 32 + lane] = av0;
        avT_out[(size_t)N * 32 + (size_t)n * 32 + lane] = av1;
        avT_out[(size_t)2 * N * 32 + (size_t)n * 32 + lane] = av2;
    }
}

// ---------------- host ----------------

extern "C" void kernel_launch(void* const* d_in, const int* in_sizes, int n_in,
                              void* d_out, int out_size, void* d_ws, size_t ws_size,
                              hipStream_t stream) {
    const float* pos    = (const float*)d_in[0];
    const float* sfeat  = (const float*)d_in[1];
    const float* vfeat  = (const float*)d_in[2];
    const float* shifts = (const float*)d_in[3];
    const int*   ei     = (const int*)d_in[4];
    const float* Ws     = (const float*)d_in[5];
    const float* Wv     = (const float*)d_in[6];
    const float* Uvs    = (const float*)d_in[7];
    const float* Usv    = (const float*)d_in[8];
    const float* Wr     = (const float*)d_in[9];
    const float* Wrb    = (const float*)d_in[10];
    const float* Wos    = (const float*)d_in[11];
    const float* Wov    = (const float*)d_in[12];
    float* out = (float*)d_out;

    const int N = in_sizes[0] / 3;
    const int E = in_sizes[4] / 2;

    char* w = (char*)d_ws;
    auto alloc = [&](size_t bytes) {
        char* p = w;
        w += (bytes + 255) & ~(size_t)255;
        return p;
    };
    int* counts   = (int*)alloc((size_t)N * 4);
    int* row_ptr  = (int*)alloc((size_t)(N + 1) * 4);
    int* cursor   = (int*)alloc((size_t)N * 4);
    float* Ms12   = (float*)alloc(2 * 4096 * 4);
    float* Mv12   = (float*)alloc(2 * 1024 * 4);
    float* spB    = (float*)alloc((size_t)N * 64 * 4);
    float* vpB    = (float*)alloc((size_t)N * 32 * 3 * 4);
    float* asB    = (float*)alloc((size_t)N * 64 * 4);
    float* avB    = (float*)alloc((size_t)N * 32 * 3 * 4);
    float* recs   = (float*)alloc((size_t)E * 20 * 4);

    hipMemsetAsync(counts, 0, (size_t)N * 4, stream);

    int eb = (E + 255) / 256;
    count_kernel<<<eb, 256, 0, stream>>>(ei, counts, E);
    scan_kernel<<<1, 1024, 0, stream>>>(counts, row_ptr, cursor, N);
    build_kernel<<<eb, 256, 0, stream>>>(ei, pos, shifts, Wr, Wrb, cursor, recs, E);
    compose_kernel<<<40, 256, 0, stream>>>(Ws, Wv, Wos, Wov, Ms12, Mv12);

    int nb = (N + 3) / 4; // 4 waves (nodes) per 256-thread block

    // layer 0
    node_transform<0><<<nb, 256, 0, stream>>>(sfeat, vfeat, Ws, Wv, spB, vpB, N);
    edge_agg<<<nb, 256, 0, stream>>>(recs, row_ptr, spB, vpB, Uvs, Usv, asB, avB, N, 5);
    // layer 1
    node_transform<1><<<nb, 256, 0, stream>>>(asB, avB, Ms12, Mv12, spB, vpB, N);
    edge_agg<<<nb, 256, 0, stream>>>(recs, row_ptr, spB, vpB, Uvs + 2048, Usv + 2048, asB, avB, N, 10);
    // layer 2
    node_transform<1><<<nb, 256, 0, stream>>>(asB, avB, Ms12 + 4096, Mv12 + 1024, spB, vpB, N);
    edge_agg<<<nb, 256, 0, stream>>>(recs, row_ptr, spB, vpB, Uvs + 4096, Usv + 4096, asB, avB, N, 15);
    // final output transform
    node_transform<2><<<nb, 256, 0, stream>>>(asB, avB, Wos + 2 * 4096, Wov + 2 * 1024, out, spB, N);
}

// Round 3
// 2701.134 us; speedup vs baseline: 1.2072x; 1.2072x over previous
//
#include <hip/hip_runtime.h>
#include <hip/hip_fp16.h>
#include <math.h>

static constexpr int HS = 64;
static constexpr int HV = 32;
static constexpr int NB = 32;
static constexpr float CUTR = 5.0f;
static constexpr float SQRT3 = 1.7320508075688772f;
static constexpr float C2C = 2.7386127875258306f; // sqrt(7.5)

union HU { unsigned u; __half2 h; };

__device__ inline unsigned pack2(float a, float b) {
    HU x;
    x.h = __halves2half2(__float2half_rn(a), __float2half_rn(b));
    return x.u;
}
__device__ inline float2 unpack2(unsigned u) {
    HU x; x.u = u;
    return __half22float2(x.h);
}

// ---------------- CSR build ----------------

__global__ void count_kernel(const int* __restrict__ ei, int* __restrict__ counts, int E) {
    int e = blockIdx.x * blockDim.x + threadIdx.x;
    if (e < E) atomicAdd(&counts[ei[E + e]], 1);
}

__global__ __launch_bounds__(1024) void scan_kernel(const int* __restrict__ counts,
                                                    int* __restrict__ row_ptr,
                                                    int* __restrict__ cursor, int N) {
    __shared__ int part[1024];
    int t = threadIdx.x;
    int chunk = (N + 1023) >> 10;
    int beg = t * chunk, end = min(beg + chunk, N);
    int s = 0;
    for (int i = beg; i < end; ++i) s += counts[i];
    part[t] = s;
    __syncthreads();
    for (int off = 1; off < 1024; off <<= 1) {
        int v = (t >= off) ? part[t - off] : 0;
        __syncthreads();
        part[t] += v;
        __syncthreads();
    }
    int base = (t == 0) ? 0 : part[t - 1];
    for (int i = beg; i < end; ++i) {
        row_ptr[i] = base;
        cursor[i] = base;
        base += counts[i];
    }
    if (t == 1023) row_ptr[N] = part[1023];
}

// Per-edge record, 16 dwords = 64B = exactly one cacheline, dst-sorted:
// [0]=src  [1..3]=d0,d1,d2 (f32)
// [4+3l .. 6+3l] = layer-l coeffs as fp16 pairs: (a,b),(c2,q3),(q4,pad)
//   a = g*w0 ; b = g*w1*sqrt3 ; c2 = g*w2*sqrt3 ; q4 = g*w4*C2 ; q3 = g*w3 - q4/3
// [13..15] = pad
__global__ void build_kernel(const int* __restrict__ ei, const float* __restrict__ pos,
                             const float* __restrict__ shifts, const float* __restrict__ Wr,
                             const float* __restrict__ Wrb, int* __restrict__ cursor,
                             unsigned* __restrict__ recs, int E) {
    int e = blockIdx.x * blockDim.x + threadIdx.x;
    if (e >= E) return;
    int src = ei[e], dst = ei[E + e];
    float ev0 = pos[dst * 3 + 0] - pos[src * 3 + 0] + shifts[e * 3 + 0];
    float ev1 = pos[dst * 3 + 1] - pos[src * 3 + 1] + shifts[e * 3 + 1];
    float ev2 = pos[dst * 3 + 2] - pos[src * 3 + 2] + shifts[e * 3 + 2];
    float r = sqrtf(ev0 * ev0 + ev1 * ev1 + ev2 * ev2);
    float rinv = 1.0f / fmaxf(r, 1e-8f);
    float d0 = ev0 * rinv, d1 = ev1 * rinv, d2 = ev2 * rinv;
    float u = r * (1.0f / CUTR);
    float gate = 0.0f;
    if (u < 1.0f) {
        float inner = 1.0f - u * u;
        gate = __expf(1.0f - 1.0f / inner);
    }
    float wacc[15];
#pragma unroll
    for (int k = 0; k < 15; ++k) wacc[k] = 0.0f;
    const float inv_w = (float)NB / CUTR; // 1/width = 6.4
    for (int b = 0; b < NB; ++b) {
        float t = (r - (float)b * (CUTR / (NB - 1))) * inv_w;
        float rb = __expf(-0.5f * t * t);
#pragma unroll
        for (int k = 0; k < 15; ++k)
            wacc[k] += rb * Wr[(k / 5) * (NB * 5) + b * 5 + (k % 5)];
    }
    unsigned rec[16];
    rec[0] = (unsigned)src;
    rec[1] = __float_as_uint(d0);
    rec[2] = __float_as_uint(d1);
    rec[3] = __float_as_uint(d2);
#pragma unroll
    for (int l = 0; l < 3; ++l) {
        float w0 = gate * wacc[l * 5 + 0] + Wrb[l * 5 + 0];
        float w1 = gate * wacc[l * 5 + 1] + Wrb[l * 5 + 1];
        float w2 = gate * wacc[l * 5 + 2] + Wrb[l * 5 + 2];
        float w3 = gate * wacc[l * 5 + 3] + Wrb[l * 5 + 3];
        float w4 = gate * wacc[l * 5 + 4] + Wrb[l * 5 + 4];
        float a  = gate * w0;
        float b  = gate * w1 * SQRT3;
        float c2 = gate * w2 * SQRT3;
        float q4 = gate * w4 * C2C;
        float q3 = gate * w3 - q4 * (1.0f / 3.0f);
        rec[4 + 3 * l] = pack2(a, b);
        rec[5 + 3 * l] = pack2(c2, q3);
        rec[6 + 3 * l] = pack2(q4, 0.0f);
    }
    rec[13] = rec[14] = rec[15] = 0u;
    int p = atomicAdd(&cursor[dst], 1);
    uint4* o = (uint4*)(recs + (size_t)p * 16);
    const uint4* s4 = (const uint4*)rec;
#pragma unroll
    for (int k = 0; k < 4; ++k) o[k] = s4[k];
}

// ---------------- weight composition:  Ms12[l] = Wos[l] @ Ws[l+1],  Mv12[l] = Wov[l] @ Wv[l+1]
__global__ void compose_kernel(const float* __restrict__ Ws, const float* __restrict__ Wv,
                               const float* __restrict__ Wos, const float* __restrict__ Wov,
                               float* __restrict__ Ms12, float* __restrict__ Mv12) {
    int t = blockIdx.x * blockDim.x + threadIdx.x;
    if (t < 2 * 4096) {
        int l = t >> 12;
        int idx = t & 4095;
        int j = idx >> 6, k = idx & 63;
        const float* A = Wos + l * 4096;
        const float* B = Ws + (l + 1) * 4096;
        float acc = 0.0f;
        for (int m = 0; m < 64; ++m) acc += A[j * 64 + m] * B[m * 64 + k];
        Ms12[t] = acc;
    } else if (t < 2 * 4096 + 2 * 1024) {
        int q = t - 2 * 4096;
        int l = q >> 10;
        int idx = q & 1023;
        int j = idx >> 5, k = idx & 31;
        const float* A = Wov + l * 1024;
        const float* B = Wv + (l + 1) * 1024;
        float acc = 0.0f;
        for (int m = 0; m < 32; ++m) acc += A[j * 32 + m] * B[m * 32 + k];
        Mv12[q] = acc;
    }
}

// ---------------- node transform: sp = as @ Ms ; vpT[d] = avT[d] @ Mv ----------------
// MODE 0: inputs raw features (s: N x 64 f32, v: N x 32 x 3 AoS f32) -> fp16 sp/vpT
// MODE 1: inputs agg buffers (as: N x 64 f32, avT: 3 planes N x 32 f32) -> fp16 sp/vpT
// MODE 2: like 1 but writes interleaved final f32 output (N x 160)
template <int MODE>
__global__ void node_transform(const float* __restrict__ s_in, const float* __restrict__ v_in,
                               const float* __restrict__ Ms, const float* __restrict__ Mv,
                               __half* __restrict__ spH, __half* __restrict__ vpH,
                               float* __restrict__ out160, int N) {
    __shared__ float sMs[64 * 64];
    __shared__ float sMv[32 * 32];
    for (int i = threadIdx.x; i < 4096; i += blockDim.x) sMs[i] = Ms[i];
    for (int i = threadIdx.x; i < 1024; i += blockDim.x) sMv[i] = Mv[i];
    __syncthreads();
    int wid = threadIdx.x >> 6, lane = threadIdx.x & 63;
    int n = blockIdx.x * (blockDim.x >> 6) + wid;
    if (n >= N) return;
    float asv = s_in[(size_t)n * 64 + lane];
    int h = lane & 31;
    float av0, av1, av2;
    if (MODE == 0) {
        av0 = v_in[(size_t)n * 96 + h * 3 + 0];
        av1 = v_in[(size_t)n * 96 + h * 3 + 1];
        av2 = v_in[(size_t)n * 96 + h * 3 + 2];
    } else {
        av0 = v_in[(size_t)n * 32 + h];
        av1 = v_in[(size_t)N * 32 + (size_t)n * 32 + h];
        av2 = v_in[(size_t)2 * N * 32 + (size_t)n * 32 + h];
    }
    float acc = 0.0f;
    for (int i = 0; i < 64; ++i)
        acc += __shfl(asv, i) * sMs[i * 64 + lane];
    float vacc0 = 0.0f, vacc1 = 0.0f, vacc2 = 0.0f;
    for (int g = 0; g < 32; ++g) {
        float b0 = __shfl(av0, g), b1 = __shfl(av1, g), b2 = __shfl(av2, g);
        float m = sMv[g * 32 + h];
        vacc0 += b0 * m; vacc1 += b1 * m; vacc2 += b2 * m;
    }
    if (MODE == 2) {
        out160[(size_t)n * 160 + lane] = acc;
        if (lane < 32) {
            out160[(size_t)n * 160 + 64 + lane * 3 + 0] = vacc0;
            out160[(size_t)n * 160 + 64 + lane * 3 + 1] = vacc1;
            out160[(size_t)n * 160 + 64 + lane * 3 + 2] = vacc2;
        }
    } else {
        spH[(size_t)n * 64 + lane] = __float2half(acc);
        if (lane < 32) {
            vpH[(size_t)n * 32 + lane] = __float2half(vacc0);
            vpH[(size_t)N * 32 + (size_t)n * 32 + lane] = __float2half(vacc1);
            vpH[(size_t)2 * N * 32 + (size_t)n * 32 + lane] = __float2half(vacc2);
        }
    }
}

// ---------------- edge aggregation: one wave per dst node, 2-edge unrolled ----------------
__global__ void edge_agg(const unsigned* __restrict__ recs, const int* __restrict__ row_ptr,
                         const __half* __restrict__ sp, const __half* __restrict__ vpT,
                         const float* __restrict__ Uvs_l, const float* __restrict__ Usv_l,
                         float* __restrict__ as_out, float* __restrict__ avT_out,
                         int N, int c0) {
    __shared__ float sUvs[32 * 64];
    __shared__ float sUsv[64 * 32];
    for (int i = threadIdx.x; i < 2048; i += blockDim.x) {
        sUvs[i] = Uvs_l[i];
        sUsv[i] = Usv_l[i];
    }
    __syncthreads();
    int wid = threadIdx.x >> 6, lane = threadIdx.x & 63;
    int n = blockIdx.x * (blockDim.x >> 6) + wid;
    if (n >= N) return;
    int beg = row_ptr[n], end = row_ptr[n + 1];
    const __half* vp0 = vpT;
    const __half* vp1 = vpT + (size_t)N * 32;
    const __half* vp2 = vpT + (size_t)2 * N * 32;
    bool lo = lane < 32;
    float S0 = 0.f, T10 = 0.f, T11 = 0.f, T12 = 0.f;
    float A1 = 0.f, V0 = 0.f, V1 = 0.f, V2 = 0.f;

    int i = beg;
    for (; i + 2 <= end; i += 2) {
        int ib = __builtin_amdgcn_readfirstlane(i);
        const unsigned* RA = recs + (size_t)ib * 16;
        const unsigned* RB = RA + 16;
        // issue all loads for both edges first
        int srcA = (int)RA[0];
        float dA0 = __uint_as_float(RA[1]), dA1 = __uint_as_float(RA[2]), dA2 = __uint_as_float(RA[3]);
        unsigned uA0 = RA[c0], uA1 = RA[c0 + 1], uA2 = RA[c0 + 2];
        int srcB = (int)RB[0];
        float dB0 = __uint_as_float(RB[1]), dB1 = __uint_as_float(RB[2]), dB2 = __uint_as_float(RB[3]);
        unsigned uB0 = RB[c0], uB1 = RB[c0 + 1], uB2 = RB[c0 + 2];
        float spcA = __half2float(sp[(size_t)srcA * 64 + lane]);
        float spcB = __half2float(sp[(size_t)srcB * 64 + lane]);
        float vA0 = 0.f, vA1 = 0.f, vA2 = 0.f, vB0 = 0.f, vB1 = 0.f, vB2 = 0.f;
        if (lo) {
            vA0 = __half2float(vp0[(size_t)srcA * 32 + lane]);
            vA1 = __half2float(vp1[(size_t)srcA * 32 + lane]);
            vA2 = __half2float(vp2[(size_t)srcA * 32 + lane]);
            vB0 = __half2float(vp0[(size_t)srcB * 32 + lane]);
            vB1 = __half2float(vp1[(size_t)srcB * 32 + lane]);
            vB2 = __half2float(vp2[(size_t)srcB * 32 + lane]);
        }
        float2 fA0 = unpack2(uA0), fA1 = unpack2(uA1), fA2 = unpack2(uA2);
        float2 fB0 = unpack2(uB0), fB1 = unpack2(uB1), fB2 = unpack2(uB2);
        // edge A
        {
            float a = fA0.x, b = fA0.y, c2 = fA1.x, q3 = fA1.y, q4 = fA2.x;
            S0 += a * spcA;
            T10 += (c2 * dA0) * spcA; T11 += (c2 * dA1) * spcA; T12 += (c2 * dA2) * spcA;
            if (lo) {
                float pdot = dA0 * vA0 + dA1 * vA1 + dA2 * vA2;
                A1 += b * pdot;
                float qp = q4 * pdot;
                V0 += q3 * vA0 + qp * dA0;
                V1 += q3 * vA1 + qp * dA1;
                V2 += q3 * vA2 + qp * dA2;
            }
        }
        // edge B
        {
            float a = fB0.x, b = fB0.y, c2 = fB1.x, q3 = fB1.y, q4 = fB2.x;
            S0 += a * spcB;
            T10 += (c2 * dB0) * spcB; T11 += (c2 * dB1) * spcB; T12 += (c2 * dB2) * spcB;
            if (lo) {
                float pdot = dB0 * vB0 + dB1 * vB1 + dB2 * vB2;
                A1 += b * pdot;
                float qp = q4 * pdot;
                V0 += q3 * vB0 + qp * dB0;
                V1 += q3 * vB1 + qp * dB1;
                V2 += q3 * vB2 + qp * dB2;
            }
        }
    }
    if (i < end) {
        int ib = __builtin_amdgcn_readfirstlane(i);
        const unsigned* RA = recs + (size_t)ib * 16;
        int srcA = (int)RA[0];
        float dA0 = __uint_as_float(RA[1]), dA1 = __uint_as_float(RA[2]), dA2 = __uint_as_float(RA[3]);
        unsigned uA0 = RA[c0], uA1 = RA[c0 + 1], uA2 = RA[c0 + 2];
        float spcA = __half2float(sp[(size_t)srcA * 64 + lane]);
        float2 f0 = unpack2(uA0), f1 = unpack2(uA1), f2 = unpack2(uA2);
        float a = f0.x, b = f0.y, c2 = f1.x, q3 = f1.y, q4 = f2.x;
        S0 += a * spcA;
        T10 += (c2 * dA0) * spcA; T11 += (c2 * dA1) * spcA; T12 += (c2 * dA2) * spcA;
        if (lo) {
            float vA0 = __half2float(vp0[(size_t)srcA * 32 + lane]);
            float vA1 = __half2float(vp1[(size_t)srcA * 32 + lane]);
            float vA2 = __half2float(vp2[(size_t)srcA * 32 + lane]);
            float pdot = dA0 * vA0 + dA1 * vA1 + dA2 * vA2;
            A1 += b * pdot;
            float qp = q4 * pdot;
            V0 += q3 * vA0 + qp * dA0;
            V1 += q3 * vA1 + qp * dA1;
            V2 += q3 * vA2 + qp * dA2;
        }
    }

    // agg_s[c] = S0 + sum_h A1[h] * Uvs[h,c]
    float aggs = S0;
    for (int h2 = 0; h2 < 32; ++h2)
        aggs += __shfl(A1, h2) * sUvs[h2 * 64 + lane];
    as_out[(size_t)n * 64 + lane] = aggs;
    // agg_v[h,d] = V[h,d] + sum_c T1[c,d] * Usv[c,h]
    float av0 = V0, av1 = V1, av2 = V2;
    int h = lane & 31;
    for (int c = 0; c < 64; ++c) {
        float uu = sUsv[c * 32 + h];
        av0 += __shfl(T10, c) * uu;
        av1 += __shfl(T11, c) * uu;
        av2 += __shfl(T12, c) * uu;
    }
    if (lo) {
        avT_out[(size_t)n * 32 + lane] = av0;
        avT_out[(size_t)N * 32 + (size_t)n * 32 + lane] = av1;
        avT_out[(size_t)2 * N * 32 + (size_t)n * 32 + lane] = av2;
    }
}

// ---------------- host ----------------

extern "C" void kernel_launch(void* const* d_in, const int* in_sizes, int n_in,
                              void* d_out, int out_size, void* d_ws, size_t ws_size,
                              hipStream_t stream) {
    const float* pos    = (const float*)d_in[0];
    const float* sfeat  = (const float*)d_in[1];
    const float* vfeat  = (const float*)d_in[2];
    const float* shifts = (const float*)d_in[3];
    const int*   ei     = (const int*)d_in[4];
    const float* Ws     = (const float*)d_in[5];
    const float* Wv     = (const float*)d_in[6];
    const float* Uvs    = (const float*)d_in[7];
    const float* Usv    = (const float*)d_in[8];
    const float* Wr     = (const float*)d_in[9];
    const float* Wrb    = (const float*)d_in[10];
    const float* Wos    = (const float*)d_in[11];
    const float* Wov    = (const float*)d_in[12];
    float* out = (float*)d_out;

    const int N = in_sizes[0] / 3;
    const int E = in_sizes[4] / 2;

    char* w = (char*)d_ws;
    auto alloc = [&](size_t bytes) {
        char* p = w;
        w += (bytes + 255) & ~(size_t)255;
        return p;
    };
    int* counts     = (int*)alloc((size_t)N * 4);
    int* row_ptr    = (int*)alloc((size_t)(N + 1) * 4);
    int* cursor     = (int*)alloc((size_t)N * 4);
    float* Ms12     = (float*)alloc(2 * 4096 * 4);
    float* Mv12     = (float*)alloc(2 * 1024 * 4);
    __half* spH     = (__half*)alloc((size_t)N * 64 * 2);
    __half* vpH     = (__half*)alloc((size_t)N * 32 * 3 * 2);
    float* asB      = (float*)alloc((size_t)N * 64 * 4);
    float* avB      = (float*)alloc((size_t)N * 32 * 3 * 4);
    unsigned* recs  = (unsigned*)alloc((size_t)E * 64);

    hipMemsetAsync(counts, 0, (size_t)N * 4, stream);

    int eb = (E + 255) / 256;
    count_kernel<<<eb, 256, 0, stream>>>(ei, counts, E);
    scan_kernel<<<1, 1024, 0, stream>>>(counts, row_ptr, cursor, N);
    build_kernel<<<eb, 256, 0, stream>>>(ei, pos, shifts, Wr, Wrb, cursor, recs, E);
    compose_kernel<<<40, 256, 0, stream>>>(Ws, Wv, Wos, Wov, Ms12, Mv12);

    int nb = (N + 3) / 4; // 4 waves (nodes) per 256-thread block

    // layer 0
    node_transform<0><<<nb, 256, 0, stream>>>(sfeat, vfeat, Ws, Wv, spH, vpH, nullptr, N);
    edge_agg<<<nb, 256, 0, stream>>>(recs, row_ptr, spH, vpH, Uvs, Usv, asB, avB, N, 4);
    // layer 1
    node_transform<1><<<nb, 256, 0, stream>>>(asB, avB, Ms12, Mv12, spH, vpH, nullptr, N);
    edge_agg<<<nb, 256, 0, stream>>>(recs, row_ptr, spH, vpH, Uvs + 2048, Usv + 2048, asB, avB, N, 7);
    // layer 2
    node_transform<1><<<nb, 256, 0, stream>>>(asB, avB, Ms12 + 4096, Mv12 + 1024, spH, vpH, nullptr, N);
    edge_agg<<<nb, 256, 0, stream>>>(recs, row_ptr, spH, vpH, Uvs + 4096, Usv + 4096, asB, avB, N, 10);
    // final output transform
    node_transform<2><<<nb, 256, 0, stream>>>(asB, avB, Wos + 2 * 4096, Wov + 2 * 1024, nullptr, nullptr, out, N);
}